// Round 3
// baseline (774.285 us; speedup 1.0000x reference)
//
#include <hip/hip_runtime.h>

// Problem constants
#define B_   32
#define C_   256
#define HW_  1024
#define N_   32768      // B_*HW_
#define M_   2000
#define MP_  2048       // M padded (rows >= 2000 are zero)
#define K_   256

typedef __attribute__((ext_vector_type(8))) _Float16 f16x8;
typedef __attribute__((ext_vector_type(4))) float f32x4;

#define KCAP 32

// ---------------- prep: mem*64 -> fp16 hi/lo split [MP_][K_] ----------------
__global__ void prep_memS_kernel(const float* __restrict__ mem,
                                 _Float16* __restrict__ mh,
                                 _Float16* __restrict__ ml) {
  int m = blockIdx.x;           // 0..2047
  int c = threadIdx.x;          // 0..255
  float v = (m < M_) ? mem[m * K_ + c] * 64.0f : 0.0f;
  _Float16 h = (_Float16)v;
  mh[m * K_ + c] = h;
  ml[m * K_ + c] = (_Float16)(v - (float)h);
}

// ---------------- fused: GEMM1 + softmax-threshold + att + sparse GEMM2 ----
// One WG = 32 pixel rows (one b, 32 consecutive hw) x ALL 2048 m.
// 8 waves; wave w owns m-strip [w*256, w*256+256). acc = 32n x 256m per wave
// = 128 VGPR/lane. e stays in registers: S (softmax denom) and S2 (kept sum)
// via shuffle + LDS cross-wave reduce. att written densely (LDS transpose
// for hw-coalescing); y via per-row kept lists (sparse GEMM2 from L2).
// eb/memset/scatter/prep_q all eliminated.
__global__ __launch_bounds__(512, 2) void fused_kernel(
    const float* __restrict__ x,
    const _Float16* __restrict__ mh, const _Float16* __restrict__ ml,
    const float* __restrict__ mem,
    float* __restrict__ y, float* __restrict__ att) {
  __shared__ float xs[256][33];           // 33.8 KB x-tile (c-major); reused as tbuf
  __shared__ _Float16 Ahs[32][264];       // 16.5 KB q hi (n-major, K-major rows, +8 pad)
  __shared__ _Float16 Als[32][264];       // 16.5 KB q lo
  __shared__ float S_part[8][32];
  __shared__ float Sthr[32];
  __shared__ float inv[32];
  __shared__ unsigned int kcnt[32];
  __shared__ unsigned int km[32][KCAP];
  __shared__ float kp[32][KCAP];

  const int tid   = threadIdx.x;
  const int lane  = tid & 63;
  const int wave  = tid >> 6;        // 0..7
  const int row16 = lane & 15;
  const int quad  = lane >> 4;
  const int n0  = blockIdx.x * 32;
  const int b   = n0 >> 10;
  const int hw0 = n0 & 1023;
  const int mw  = wave * 256;        // wave's m-strip base

  // ---- stage x[b][*][hw0..hw0+31] -> xs (coalesced), init kcnt ----
  {
    const int c = tid >> 1;
    const int h16 = (tid & 1) * 16;
    const float* src = x + ((size_t)b * C_ + c) * HW_ + hw0 + h16;
#pragma unroll
    for (int i = 0; i < 4; ++i)
      *(f32x4*)(&xs[c][h16 + i * 4]) = *(const f32x4*)(src + i * 4);
  }
  if (tid < 32) kcnt[tid] = 0;
  __syncthreads();

  // ---- transpose-convert xs -> Ahs/Als (fp16 hi/lo, n-major) ----
  {
    const int nl = tid >> 4;             // 0..31
    const int cg = (tid & 15) * 16;      // 0..240
    f16x8 hi0, hi1, lo0, lo1;
#pragma unroll
    for (int u = 0; u < 8; ++u) {
      float v = xs[cg + u][nl];
      _Float16 h = (_Float16)v;
      hi0[u] = h; lo0[u] = (_Float16)(v - (float)h);
    }
#pragma unroll
    for (int u = 0; u < 8; ++u) {
      float v = xs[cg + 8 + u][nl];
      _Float16 h = (_Float16)v;
      hi1[u] = h; lo1[u] = (_Float16)(v - (float)h);
    }
    *(f16x8*)(&Ahs[nl][cg])     = hi0;
    *(f16x8*)(&Ahs[nl][cg + 8]) = hi1;
    *(f16x8*)(&Als[nl][cg])     = lo0;
    *(f16x8*)(&Als[nl][cg + 8]) = lo1;
  }
  __syncthreads();

  // ---- GEMM: acc[i][j] = 64*(q . mem), 3-pass fp16 split, barrier-free ----
  f32x4 acc[2][16];
#pragma unroll
  for (int i = 0; i < 2; ++i)
#pragma unroll
    for (int j = 0; j < 16; ++j) acc[i][j] = (f32x4){0.f, 0.f, 0.f, 0.f};

  const _Float16* mhp = mh + (size_t)(mw + row16) * K_ + quad * 8;
  const _Float16* mlp = ml + (size_t)(mw + row16) * K_ + quad * 8;

#pragma unroll 1
  for (int ks = 0; ks < 8; ++ks) {
    const int ko = ks * 32 + quad * 8;
    f16x8 ah0 = *(const f16x8*)(&Ahs[row16][ko]);
    f16x8 ah1 = *(const f16x8*)(&Ahs[16 + row16][ko]);
    f16x8 al0 = *(const f16x8*)(&Als[row16][ko]);
    f16x8 al1 = *(const f16x8*)(&Als[16 + row16][ko]);
#pragma unroll
    for (int jg = 0; jg < 2; ++jg) {
      f16x8 bh[8], bl[8];
#pragma unroll
      for (int u = 0; u < 8; ++u) {
        const int j = jg * 8 + u;
        bh[u] = *(const f16x8*)(mhp + (size_t)j * 16 * K_ + ks * 32);
        bl[u] = *(const f16x8*)(mlp + (size_t)j * 16 * K_ + ks * 32);
      }
#pragma unroll
      for (int u = 0; u < 8; ++u) {
        const int j = jg * 8 + u;
        acc[0][j] = __builtin_amdgcn_mfma_f32_16x16x32_f16(ah0, bh[u], acc[0][j], 0, 0, 0);
        acc[1][j] = __builtin_amdgcn_mfma_f32_16x16x32_f16(ah1, bh[u], acc[1][j], 0, 0, 0);
        acc[0][j] = __builtin_amdgcn_mfma_f32_16x16x32_f16(al0, bh[u], acc[0][j], 0, 0, 0);
        acc[1][j] = __builtin_amdgcn_mfma_f32_16x16x32_f16(al1, bh[u], acc[1][j], 0, 0, 0);
        acc[0][j] = __builtin_amdgcn_mfma_f32_16x16x32_f16(ah0, bl[u], acc[0][j], 0, 0, 0);
        acc[1][j] = __builtin_amdgcn_mfma_f32_16x16x32_f16(ah1, bl[u], acc[1][j], 0, 0, 0);
      }
    }
  }

  // ---- exp (mask padded m >= 2000: wave 7, j >= 13) ----
  const int maskj = (mw + 256 > M_) ? (M_ - mw) / 16 : 16;   // 13 for wave 7
#pragma unroll
  for (int i = 0; i < 2; ++i)
#pragma unroll
    for (int j = 0; j < 16; ++j)
#pragma unroll
      for (int r = 0; r < 4; ++r)
        acc[i][j][r] = (j < maskj) ? __expf(acc[i][j][r] * 0.015625f) : 0.f;

  // ---- S = row sums (in-reg + 16-lane shuffle + cross-wave LDS) ----
  const int nlb = quad * 4;   // acc row r of frag i -> n_local = i*16 + nlb + r
#pragma unroll
  for (int i = 0; i < 2; ++i)
#pragma unroll
    for (int r = 0; r < 4; ++r) {
      float s = 0.f;
#pragma unroll
      for (int j = 0; j < 16; ++j) s += acc[i][j][r];
      s += __shfl_xor(s, 1, 16);
      s += __shfl_xor(s, 2, 16);
      s += __shfl_xor(s, 4, 16);
      s += __shfl_xor(s, 8, 16);
      if (row16 == 0) S_part[wave][i * 16 + nlb + r] = s;
    }
  __syncthreads();
  if (tid < 32) {
    float s = 0.f;
#pragma unroll
    for (int w = 0; w < 8; ++w) s += S_part[w][tid];
    Sthr[tid] = 0.0025f * s;
  }
  __syncthreads();

  // ---- S2 = sum of kept e; append kept (m, e) to per-row lists ----
#pragma unroll
  for (int i = 0; i < 2; ++i)
#pragma unroll
    for (int r = 0; r < 4; ++r) {
      const int nl = i * 16 + nlb + r;
      const float thr = Sthr[nl];
      float s2 = 0.f;
#pragma unroll
      for (int j = 0; j < 16; ++j) {
        const float e = acc[i][j][r];
        if (e > thr) {
          s2 += e;
          unsigned int pos = atomicAdd(&kcnt[nl], 1u);
          if (pos < (unsigned)KCAP) {
            km[nl][pos] = (unsigned)(mw + j * 16 + row16);
            kp[nl][pos] = e;
          }
        }
      }
      s2 += __shfl_xor(s2, 1, 16);
      s2 += __shfl_xor(s2, 2, 16);
      s2 += __shfl_xor(s2, 4, 16);
      s2 += __shfl_xor(s2, 8, 16);
      if (row16 == 0) S_part[wave][nl] = s2;
    }
  __syncthreads();
  if (tid < 32) {
    float s2 = 0.f;
#pragma unroll
    for (int w = 0; w < 8; ++w) s2 += S_part[w][tid];
    inv[tid] = (s2 > 0.f) ? 1.0f / s2 : 0.f;
  }
  __syncthreads();

  // ---- scale acc to final p (0 below threshold) ----
#pragma unroll
  for (int i = 0; i < 2; ++i)
#pragma unroll
    for (int r = 0; r < 4; ++r) {
      const int nl = i * 16 + nlb + r;
      const float thr = Sthr[nl];
      const float iv = inv[nl];
#pragma unroll
      for (int j = 0; j < 16; ++j) {
        const float e = acc[i][j][r];
        acc[i][j][r] = (e > thr) ? e * iv : 0.f;
      }
    }

  // ---- dense att store, transposed through per-wave LDS buffer ----
  // tbuf overlays xs (dead after A-staging). [8 waves][16 m][35 pad] f32.
  float (*tbuf)[16][35] = (float (*)[16][35])(&xs[0][0]);
  float* attb = att + (size_t)b * M_ * HW_ + hw0;
  const int shw = lane & 31;
  const int sm0 = lane >> 5;
#pragma unroll 1
  for (int j = 0; j < 16; ++j) {
    if (j >= maskj) break;                 // wave-uniform (skip padded m)
#pragma unroll
    for (int i = 0; i < 2; ++i)
#pragma unroll
      for (int r = 0; r < 4; ++r)
        tbuf[wave][row16][i * 16 + nlb + r] = acc[i][j][r];
    // same-wave LDS RAW: compiler inserts lgkmcnt wait
#pragma unroll
    for (int k = 0; k < 8; ++k) {
      const int mr = sm0 + k * 2;
      attb[(size_t)(mw + j * 16 + mr) * HW_ + shw] = tbuf[wave][mr][shw];
    }
  }

  // ---- y: sparse GEMM2 from kept lists (mem is L2-resident) ----
  {
    const int hwL = tid & 31;
    const int cq  = tid >> 5;              // 0..15
    unsigned int kc = kcnt[hwL];
    if (kc > (unsigned)KCAP) kc = KCAP;
    const float iv = inv[hwL];
    float* yb = y + (size_t)b * C_ * HW_ + hw0 + hwL;
#pragma unroll 1
    for (int ci = 0; ci < 16; ++ci) {
      const int c = ci * 16 + cq;
      float yv = 0.f;
      for (unsigned int k = 0; k < kc; ++k)
        yv += kp[hwL][k] * mem[(size_t)km[hwL][k] * K_ + c];
      yb[(size_t)c * HW_] = yv * iv;
    }
  }
}

// ---------------- host ----------------
extern "C" void kernel_launch(void* const* d_in, const int* in_sizes, int n_in,
                              void* d_out, int out_size, void* d_ws, size_t ws_size,
                              hipStream_t stream) {
  const float* x   = (const float*)d_in[0];      // [32,256,32,32]
  const float* mem = (const float*)d_in[1];      // [2000,256]
  float* y       = (float*)d_out;                              // 8388608 floats
  float* att_out = (float*)d_out + (size_t)B_ * C_ * HW_;      // 65536000 floats

  char* ws = (char*)d_ws;
  _Float16* mh = (_Float16*)ws;                                // 1 MB
  _Float16* ml = (_Float16*)(ws + (size_t)1024 * 1024);        // 1 MB

  prep_memS_kernel<<<dim3(MP_), dim3(K_), 0, stream>>>(mem, mh, ml);
  fused_kernel<<<dim3(N_ / 32), dim3(512), 0, stream>>>(
      x, mh, ml, mem, y, att_out);
}

// Round 4
// 669.397 us; speedup vs baseline: 1.1567x; 1.1567x over previous
//
#include <hip/hip_runtime.h>

// Problem constants
#define B_   32
#define C_   256
#define HW_  1024
#define N_   32768      // B_*HW_
#define M_   2000
#define MP_  2048       // M padded (rows >= 2000 are zero)
#define K_   256

typedef __attribute__((ext_vector_type(8))) _Float16 f16x8;
typedef __attribute__((ext_vector_type(4))) float f32x4;

#define KCAP 32
#define AP   266        // Ahs/Als row stride in halfwords (266 = 133 words, odd -> 2-way max)

// ---------------- prep: mem*64 -> fp16 hi/lo split, K-PERMUTED ------------
// Stored position p holds logical channel c(p) = 16*(p&15) + (p>>4) (nibble
// swap, an involution). Both GEMM operands consume the same permuted K order,
// so dot products are unchanged; the permutation makes the fused kernel's
// x-transpose read CONSECUTIVE LDS rows per 16-lane group (conflict-free-ish)
// instead of 16-strided rows (8-way conflict).
__global__ void prep_memS_kernel(const float* __restrict__ mem,
                                 _Float16* __restrict__ mh,
                                 _Float16* __restrict__ ml) {
  int m = blockIdx.x;           // 0..2047
  int p = threadIdx.x;          // 0..255 (stored position)
  int c = ((p & 15) << 4) | (p >> 4);
  float v = (m < M_) ? mem[m * K_ + c] * 64.0f : 0.0f;
  _Float16 h = (_Float16)v;
  mh[m * K_ + p] = h;
  ml[m * K_ + p] = (_Float16)(v - (float)h);
}

// ---------------- fused: GEMM1 + softmax-threshold + att + sparse GEMM2 ----
// One WG = 32 pixel rows (one b, 32 consecutive hw) x ALL 2048 m.
// 8 waves; wave w owns m-strip [w*256, w*256+256). acc = 32n x 256m per wave
// = 128 regs/lane (AGPR). e stays in registers; S and S2 via shuffle + LDS
// cross-wave reduce. att written densely (LDS transpose for hw-coalescing);
// y via per-row kept lists (sparse GEMM2 from L2).
__global__ __launch_bounds__(512, 1) void fused_kernel(
    const float* __restrict__ x,
    const _Float16* __restrict__ mh, const _Float16* __restrict__ ml,
    const float* __restrict__ mem,
    float* __restrict__ y, float* __restrict__ att) {
  __shared__ float xs[256][33];           // 33.8 KB x-tile (c-major); reused as tbuf
  __shared__ _Float16 Ahs[32][AP];        // q hi (n-major, permuted-K rows)
  __shared__ _Float16 Als[32][AP];        // q lo
  __shared__ float S_part[8][32];
  __shared__ float Sthr[32];
  __shared__ float inv[32];
  __shared__ unsigned int kcnt[32];
  __shared__ unsigned int km[32][KCAP];
  __shared__ float kp[32][KCAP];

  const int tid   = threadIdx.x;
  const int lane  = tid & 63;
  const int wave  = tid >> 6;        // 0..7
  const int row16 = lane & 15;
  const int quad  = lane >> 4;
  const int n0  = blockIdx.x * 32;
  const int b   = n0 >> 10;
  const int hw0 = n0 & 1023;
  const int mw  = wave * 256;        // wave's m-strip base

  // ---- stage x[b][*][hw0..hw0+31] -> xs (coalesced), init kcnt ----
  {
    const int c = tid >> 1;
    const int h16 = (tid & 1) * 16;
    const float* src = x + ((size_t)b * C_ + c) * HW_ + hw0 + h16;
#pragma unroll
    for (int i = 0; i < 4; ++i)
      *(f32x4*)(&xs[c][h16 + i * 4]) = *(const f32x4*)(src + i * 4);
  }
  if (tid < 32) kcnt[tid] = 0;
  __syncthreads();

  // ---- transpose-convert xs -> Ahs/Als (fp16 hi/lo, n-major, permuted K) --
  // Lane g (= tid&15) fills stored positions p = 16g..16g+15 of row nl; the
  // logical channel for p = 16g+u is c = 16u+g, so iteration u reads xs row
  // 16u+g: the 16 lanes of a group hit 16 CONSECUTIVE rows -> banks spread.
  {
    const int nl = tid >> 4;             // 0..31
    const int g  = tid & 15;
    f16x8 hi0, hi1, lo0, lo1;
#pragma unroll
    for (int u = 0; u < 8; ++u) {
      float v = xs[u * 16 + g][nl];
      _Float16 h = (_Float16)v;
      hi0[u] = h; lo0[u] = (_Float16)(v - (float)h);
    }
#pragma unroll
    for (int u = 0; u < 8; ++u) {
      float v = (u + 8) * 16 + g < 256 ? xs[(u + 8) * 16 + g][nl] : 0.f;
      _Float16 h = (_Float16)v;
      hi1[u] = h; lo1[u] = (_Float16)(v - (float)h);
    }
    *(f16x8*)(&Ahs[nl][g * 16])     = hi0;
    *(f16x8*)(&Ahs[nl][g * 16 + 8]) = hi1;
    *(f16x8*)(&Als[nl][g * 16])     = lo0;
    *(f16x8*)(&Als[nl][g * 16 + 8]) = lo1;
  }
  __syncthreads();

  // ---- GEMM: acc = 64*(q . mem), 3-pass fp16 split, barrier-free ----
  f32x4 acc[2][16];
#pragma unroll
  for (int i = 0; i < 2; ++i)
#pragma unroll
    for (int j = 0; j < 16; ++j) acc[i][j] = (f32x4){0.f, 0.f, 0.f, 0.f};

  const _Float16* mhp = mh + (size_t)(mw + row16) * K_ + quad * 8;
  const _Float16* mlp = ml + (size_t)(mw + row16) * K_ + quad * 8;

#pragma unroll 1
  for (int ks = 0; ks < 8; ++ks) {
    const int ko = ks * 32 + quad * 8;
    f16x8 ah0 = *(const f16x8*)(&Ahs[row16][ko]);
    f16x8 ah1 = *(const f16x8*)(&Ahs[16 + row16][ko]);
    f16x8 al0 = *(const f16x8*)(&Als[row16][ko]);
    f16x8 al1 = *(const f16x8*)(&Als[16 + row16][ko]);
#pragma unroll
    for (int jg = 0; jg < 2; ++jg) {
      f16x8 bh[8], bl[8];
#pragma unroll
      for (int u = 0; u < 8; ++u) {
        const int j = jg * 8 + u;
        bh[u] = *(const f16x8*)(mhp + (size_t)j * 16 * K_ + ks * 32);
        bl[u] = *(const f16x8*)(mlp + (size_t)j * 16 * K_ + ks * 32);
      }
#pragma unroll
      for (int u = 0; u < 8; ++u) {
        const int j = jg * 8 + u;
        acc[0][j] = __builtin_amdgcn_mfma_f32_16x16x32_f16(ah0, bh[u], acc[0][j], 0, 0, 0);
        acc[1][j] = __builtin_amdgcn_mfma_f32_16x16x32_f16(ah1, bh[u], acc[1][j], 0, 0, 0);
        acc[0][j] = __builtin_amdgcn_mfma_f32_16x16x32_f16(al0, bh[u], acc[0][j], 0, 0, 0);
        acc[1][j] = __builtin_amdgcn_mfma_f32_16x16x32_f16(al1, bh[u], acc[1][j], 0, 0, 0);
        acc[0][j] = __builtin_amdgcn_mfma_f32_16x16x32_f16(ah0, bl[u], acc[0][j], 0, 0, 0);
        acc[1][j] = __builtin_amdgcn_mfma_f32_16x16x32_f16(ah1, bl[u], acc[1][j], 0, 0, 0);
      }
    }
  }

  // ---- exp (mask padded m >= 2000: wave 7, j >= 13) ----
  const int maskj = (mw + 256 > M_) ? (M_ - mw) / 16 : 16;   // 13 for wave 7
#pragma unroll
  for (int i = 0; i < 2; ++i)
#pragma unroll
    for (int j = 0; j < 16; ++j)
#pragma unroll
      for (int r = 0; r < 4; ++r)
        acc[i][j][r] = (j < maskj) ? __expf(acc[i][j][r] * 0.015625f) : 0.f;

  // ---- S = row sums (in-reg + 16-lane shuffle + cross-wave LDS) ----
  const int nlb = quad * 4;   // acc row r of frag i -> n_local = i*16 + nlb + r
#pragma unroll
  for (int i = 0; i < 2; ++i)
#pragma unroll
    for (int r = 0; r < 4; ++r) {
      float s = 0.f;
#pragma unroll
      for (int j = 0; j < 16; ++j) s += acc[i][j][r];
      s += __shfl_xor(s, 1, 16);
      s += __shfl_xor(s, 2, 16);
      s += __shfl_xor(s, 4, 16);
      s += __shfl_xor(s, 8, 16);
      if (row16 == 0) S_part[wave][i * 16 + nlb + r] = s;
    }
  __syncthreads();
  if (tid < 32) {
    float s = 0.f;
#pragma unroll
    for (int w = 0; w < 8; ++w) s += S_part[w][tid];
    Sthr[tid] = 0.0025f * s;
  }
  __syncthreads();

  // ---- S2 = sum of kept e; append kept (m, e) to per-row lists ----
#pragma unroll
  for (int i = 0; i < 2; ++i)
#pragma unroll
    for (int r = 0; r < 4; ++r) {
      const int nl = i * 16 + nlb + r;
      const float thr = Sthr[nl];
      float s2 = 0.f;
#pragma unroll
      for (int j = 0; j < 16; ++j) {
        const float e = acc[i][j][r];
        if (e > thr) {
          s2 += e;
          unsigned int pos = atomicAdd(&kcnt[nl], 1u);
          if (pos < (unsigned)KCAP) {
            km[nl][pos] = (unsigned)(mw + j * 16 + row16);
            kp[nl][pos] = e;
          }
        }
      }
      s2 += __shfl_xor(s2, 1, 16);
      s2 += __shfl_xor(s2, 2, 16);
      s2 += __shfl_xor(s2, 4, 16);
      s2 += __shfl_xor(s2, 8, 16);
      if (row16 == 0) S_part[wave][nl] = s2;
    }
  __syncthreads();
  if (tid < 32) {
    float s2 = 0.f;
#pragma unroll
    for (int w = 0; w < 8; ++w) s2 += S_part[w][tid];
    inv[tid] = (s2 > 0.f) ? 1.0f / s2 : 0.f;
  }
  __syncthreads();

  // ---- scale acc to final p (0 below threshold) ----
#pragma unroll
  for (int i = 0; i < 2; ++i)
#pragma unroll
    for (int r = 0; r < 4; ++r) {
      const int nl = i * 16 + nlb + r;
      const float thr = Sthr[nl];
      const float iv = inv[nl];
#pragma unroll
      for (int j = 0; j < 16; ++j) {
        const float e = acc[i][j][r];
        acc[i][j][r] = (e > thr) ? e * iv : 0.f;
      }
    }

  // ---- dense att store, transposed through per-wave LDS buffer ----
  // tbuf overlays xs (dead after A-staging). [8 waves][16 m][35 pad] f32.
  // j is FULLY UNROLLED (compile-time) so acc stays in registers (rule #20:
  // runtime-indexed ext_vector arrays demote to scratch -- the R3 bug).
  float (*tbuf)[16][35] = (float (*)[16][35])(&xs[0][0]);
  float* attb = att + (size_t)b * M_ * HW_ + hw0;
  const int shw = lane & 31;
  const int sm0 = lane >> 5;
#pragma unroll
  for (int j = 0; j < 16; ++j) {
    if (mw + j * 16 < M_) {              // wave-uniform predicate (skip padded m)
#pragma unroll
      for (int i = 0; i < 2; ++i)
#pragma unroll
        for (int r = 0; r < 4; ++r)
          tbuf[wave][row16][i * 16 + nlb + r] = acc[i][j][r];
      // same-wave LDS RAW: compiler inserts lgkmcnt wait
#pragma unroll
      for (int k = 0; k < 8; ++k) {
        const int mr = sm0 + k * 2;
        attb[(size_t)(mw + j * 16 + mr) * HW_ + shw] = tbuf[wave][mr][shw];
      }
    }
  }

  // ---- y: sparse GEMM2 from kept lists (mem is L2-resident) ----
  {
    const int hwL = tid & 31;
    const int cq  = tid >> 5;              // 0..15
    unsigned int kc = kcnt[hwL];
    if (kc > (unsigned)KCAP) kc = KCAP;
    const float iv = inv[hwL];
    float* yb = y + (size_t)b * C_ * HW_ + hw0 + hwL;
#pragma unroll 1
    for (int ci = 0; ci < 16; ++ci) {
      const int c = ci * 16 + cq;
      float yv = 0.f;
      for (unsigned int k = 0; k < kc; ++k)
        yv += kp[hwL][k] * mem[(size_t)km[hwL][k] * K_ + c];
      yb[(size_t)c * HW_] = yv * iv;
    }
  }
}

// ---------------- host ----------------
extern "C" void kernel_launch(void* const* d_in, const int* in_sizes, int n_in,
                              void* d_out, int out_size, void* d_ws, size_t ws_size,
                              hipStream_t stream) {
  const float* x   = (const float*)d_in[0];      // [32,256,32,32]
  const float* mem = (const float*)d_in[1];      // [2000,256]
  float* y       = (float*)d_out;                              // 8388608 floats
  float* att_out = (float*)d_out + (size_t)B_ * C_ * HW_;      // 65536000 floats

  char* ws = (char*)d_ws;
  _Float16* mh = (_Float16*)ws;                                // 1 MB
  _Float16* ml = (_Float16*)(ws + (size_t)1024 * 1024);        // 1 MB

  prep_memS_kernel<<<dim3(MP_), dim3(K_), 0, stream>>>(mem, mh, ml);
  fused_kernel<<<dim3(N_ / 32), dim3(512), 0, stream>>>(
      x, mh, ml, mem, y, att_out);
}

// Round 5
// 614.584 us; speedup vs baseline: 1.2599x; 1.0892x over previous
//
#include <hip/hip_runtime.h>

// Problem constants
#define B_   32
#define C_   256
#define HW_  1024
#define N_   32768      // B_*HW_
#define M_   2000
#define MP_  2048       // M padded (rows >= 2000 are zero)
#define K_   256

typedef __attribute__((ext_vector_type(8))) _Float16 f16x8;
typedef __attribute__((ext_vector_type(4))) float f32x4;

#define KCAP 32
#define AP   266        // Ahs/Als row stride in halfwords (odd word count)

// ---------------- prep: mem*64 -> fp16 hi/lo split, K-PERMUTED ------------
// Stored position p holds logical channel c(p) = 16*(p&15) + (p>>4) (nibble
// swap involution). Both GEMM operands use the same permuted K order, so dot
// products are unchanged; the fused kernel's x-transpose then reads
// consecutive xs rows per 16-lane group.
__global__ void prep_memS_kernel(const float* __restrict__ mem,
                                 _Float16* __restrict__ mh,
                                 _Float16* __restrict__ ml) {
  int m = blockIdx.x;           // 0..2047
  int p = threadIdx.x;          // 0..255 (stored position)
  int c = ((p & 15) << 4) | (p >> 4);
  float v = (m < M_) ? mem[m * K_ + c] * 64.0f : 0.0f;
  _Float16 h = (_Float16)v;
  mh[m * K_ + p] = h;
  ml[m * K_ + p] = (_Float16)(v - (float)h);
}

// ---------------- fused: GEMM1 + softmax-threshold + att + sparse GEMM2 ----
// One WG = 32 pixel rows (one b, 32 consecutive hw) x ALL 2048 m.
// 8 waves; wave w owns m-strip [w*256, w*256+256). acc = 32n x 256m per wave
// (128 regs/lane, AGPR). S and S2 via shuffle + LDS cross-wave reduce.
// att stored DIRECTLY from acc (f32x4 per lane; hw is contiguous in acc's
// r index) -- no LDS round-trip. y via per-row kept lists, k-outer/ci-inner
// interchange for 16-deep MLP.
__global__ __launch_bounds__(512, 1) void fused_kernel(
    const float* __restrict__ x,
    const _Float16* __restrict__ mh, const _Float16* __restrict__ ml,
    const float* __restrict__ mem,
    float* __restrict__ y, float* __restrict__ att) {
  __shared__ float xs[256][33];           // 33.8 KB x-tile (c-major)
  __shared__ _Float16 Ahs[32][AP];        // q hi (n-major, permuted-K rows)
  __shared__ _Float16 Als[32][AP];        // q lo
  __shared__ float S_part[8][32];
  __shared__ float Sthr[32];
  __shared__ float inv[32];
  __shared__ unsigned int kcnt[32];
  __shared__ unsigned int km[32][KCAP];
  __shared__ float kp[32][KCAP];

  const int tid   = threadIdx.x;
  const int lane  = tid & 63;
  const int wave  = tid >> 6;        // 0..7
  const int row16 = lane & 15;
  const int quad  = lane >> 4;
  const int n0  = blockIdx.x * 32;
  const int b   = n0 >> 10;
  const int hw0 = n0 & 1023;
  const int mw  = wave * 256;        // wave's m-strip base

  // ---- stage x[b][*][hw0..hw0+31] -> xs (coalesced), init kcnt ----
  {
    const int c = tid >> 1;
    const int h16 = (tid & 1) * 16;
    const float* src = x + ((size_t)b * C_ + c) * HW_ + hw0 + h16;
#pragma unroll
    for (int i = 0; i < 4; ++i)
      *(f32x4*)(&xs[c][h16 + i * 4]) = *(const f32x4*)(src + i * 4);
  }
  if (tid < 32) kcnt[tid] = 0;
  __syncthreads();

  // ---- transpose-convert xs -> Ahs/Als (fp16 hi/lo, n-major, permuted K) --
  {
    const int nl = tid >> 4;             // 0..31
    const int g  = tid & 15;
    f16x8 hi0, hi1, lo0, lo1;
#pragma unroll
    for (int u = 0; u < 8; ++u) {
      float v = xs[u * 16 + g][nl];
      _Float16 h = (_Float16)v;
      hi0[u] = h; lo0[u] = (_Float16)(v - (float)h);
    }
#pragma unroll
    for (int u = 0; u < 8; ++u) {
      float v = xs[(u + 8) * 16 + g][nl];
      _Float16 h = (_Float16)v;
      hi1[u] = h; lo1[u] = (_Float16)(v - (float)h);
    }
    *(f16x8*)(&Ahs[nl][g * 16])     = hi0;
    *(f16x8*)(&Ahs[nl][g * 16 + 8]) = hi1;
    *(f16x8*)(&Als[nl][g * 16])     = lo0;
    *(f16x8*)(&Als[nl][g * 16 + 8]) = lo1;
  }
  __syncthreads();

  // ---- GEMM: acc = 64*(q . mem), 3-pass fp16 split, barrier-free ----
  f32x4 acc[2][16];
#pragma unroll
  for (int i = 0; i < 2; ++i)
#pragma unroll
    for (int j = 0; j < 16; ++j) acc[i][j] = (f32x4){0.f, 0.f, 0.f, 0.f};

  const _Float16* mhp = mh + (size_t)(mw + row16) * K_ + quad * 8;
  const _Float16* mlp = ml + (size_t)(mw + row16) * K_ + quad * 8;

#pragma unroll 1
  for (int ks = 0; ks < 8; ++ks) {
    const int ko = ks * 32 + quad * 8;
    f16x8 ah0 = *(const f16x8*)(&Ahs[row16][ko]);
    f16x8 ah1 = *(const f16x8*)(&Ahs[16 + row16][ko]);
    f16x8 al0 = *(const f16x8*)(&Als[row16][ko]);
    f16x8 al1 = *(const f16x8*)(&Als[16 + row16][ko]);
#pragma unroll
    for (int jg = 0; jg < 2; ++jg) {
      f16x8 bh[8], bl[8];
#pragma unroll
      for (int u = 0; u < 8; ++u) {
        const int j = jg * 8 + u;
        bh[u] = *(const f16x8*)(mhp + (size_t)j * 16 * K_ + ks * 32);
        bl[u] = *(const f16x8*)(mlp + (size_t)j * 16 * K_ + ks * 32);
      }
#pragma unroll
      for (int u = 0; u < 8; ++u) {
        const int j = jg * 8 + u;
        acc[0][j] = __builtin_amdgcn_mfma_f32_16x16x32_f16(ah0, bh[u], acc[0][j], 0, 0, 0);
        acc[1][j] = __builtin_amdgcn_mfma_f32_16x16x32_f16(ah1, bh[u], acc[1][j], 0, 0, 0);
        acc[0][j] = __builtin_amdgcn_mfma_f32_16x16x32_f16(al0, bh[u], acc[0][j], 0, 0, 0);
        acc[1][j] = __builtin_amdgcn_mfma_f32_16x16x32_f16(al1, bh[u], acc[1][j], 0, 0, 0);
        acc[0][j] = __builtin_amdgcn_mfma_f32_16x16x32_f16(ah0, bl[u], acc[0][j], 0, 0, 0);
        acc[1][j] = __builtin_amdgcn_mfma_f32_16x16x32_f16(ah1, bl[u], acc[1][j], 0, 0, 0);
      }
    }
  }

  // ---- exp (mask padded m >= 2000: wave 7, j >= 13) ----
  const int maskj = (mw + 256 > M_) ? (M_ - mw) / 16 : 16;   // 13 for wave 7
#pragma unroll
  for (int i = 0; i < 2; ++i)
#pragma unroll
    for (int j = 0; j < 16; ++j)
#pragma unroll
      for (int r = 0; r < 4; ++r)
        acc[i][j][r] = (j < maskj) ? __expf(acc[i][j][r] * 0.015625f) : 0.f;

  // ---- S = row sums (in-reg + 16-lane shuffle + cross-wave LDS) ----
  const int nlb = quad * 4;   // acc row r of frag i -> n_local = i*16 + nlb + r
#pragma unroll
  for (int i = 0; i < 2; ++i)
#pragma unroll
    for (int r = 0; r < 4; ++r) {
      float s = 0.f;
#pragma unroll
      for (int j = 0; j < 16; ++j) s += acc[i][j][r];
      s += __shfl_xor(s, 1, 16);
      s += __shfl_xor(s, 2, 16);
      s += __shfl_xor(s, 4, 16);
      s += __shfl_xor(s, 8, 16);
      if (row16 == 0) S_part[wave][i * 16 + nlb + r] = s;
    }
  __syncthreads();
  if (tid < 32) {
    float s = 0.f;
#pragma unroll
    for (int w = 0; w < 8; ++w) s += S_part[w][tid];
    Sthr[tid] = 0.0025f * s;
  }
  __syncthreads();

  // ---- S2 = sum of kept e; append kept (m, e) to per-row lists ----
#pragma unroll
  for (int i = 0; i < 2; ++i)
#pragma unroll
    for (int r = 0; r < 4; ++r) {
      const int nl = i * 16 + nlb + r;
      const float thr = Sthr[nl];
      float s2 = 0.f;
#pragma unroll
      for (int j = 0; j < 16; ++j) {
        const float e = acc[i][j][r];
        if (e > thr) {
          s2 += e;
          unsigned int pos = atomicAdd(&kcnt[nl], 1u);
          if (pos < (unsigned)KCAP) {
            km[nl][pos] = (unsigned)(mw + j * 16 + row16);
            kp[nl][pos] = e;
          }
        }
      }
      s2 += __shfl_xor(s2, 1, 16);
      s2 += __shfl_xor(s2, 2, 16);
      s2 += __shfl_xor(s2, 4, 16);
      s2 += __shfl_xor(s2, 8, 16);
      if (row16 == 0) S_part[wave][nl] = s2;
    }
  __syncthreads();
  if (tid < 32) {
    float s2 = 0.f;
#pragma unroll
    for (int w = 0; w < 8; ++w) s2 += S_part[w][tid];
    inv[tid] = (s2 > 0.f) ? 1.0f / s2 : 0.f;
  }
  __syncthreads();

  // ---- scale acc to final p (0 below threshold) ----
#pragma unroll
  for (int i = 0; i < 2; ++i)
#pragma unroll
    for (int r = 0; r < 4; ++r) {
      const int nl = i * 16 + nlb + r;
      const float thr = Sthr[nl];
      const float iv = inv[nl];
#pragma unroll
      for (int j = 0; j < 16; ++j) {
        const float e = acc[i][j][r];
        acc[i][j][r] = (e > thr) ? e * iv : 0.f;
      }
    }

  // ---- att store: DIRECT from acc, vectorized ----
  // acc[i][j] holds (n = i*16 + quad*4 + r, m = j*16 + row16); r-values are
  // consecutive hw -> one global_store_dwordx4 per (i,j). 26 stores/lane,
  // no LDS round-trip (R4's tbuf was a serialized lgkm chain + conflicts).
  {
    float* attb = att + (size_t)b * M_ * HW_ + hw0;
#pragma unroll
    for (int j = 0; j < 16; ++j) {
      if (mw + j * 16 < M_) {            // wave-uniform (skip padded m)
        float* ar = attb + (size_t)(mw + j * 16 + row16) * HW_ + nlb;
        *(f32x4*)(ar)      = acc[0][j];
        *(f32x4*)(ar + 16) = acc[1][j];
      }
    }
  }

  // ---- y: sparse GEMM2, k-outer / ci-inner for 16-deep MLP ----
  {
    const int hwL = tid & 31;
    const int cq  = tid >> 5;              // 0..15
    unsigned int kc = kcnt[hwL];
    if (kc > (unsigned)KCAP) kc = KCAP;
    const float iv = inv[hwL];
    float yv[16];
#pragma unroll
    for (int ci = 0; ci < 16; ++ci) yv[ci] = 0.f;
#pragma unroll 1
    for (unsigned int k = 0; k < kc; ++k) {
      const float p = kp[hwL][k];
      const float* mrow = mem + (size_t)km[hwL][k] * K_ + cq;
#pragma unroll
      for (int ci = 0; ci < 16; ++ci)
        yv[ci] += p * mrow[ci * 16];       // 16 independent L2 loads in flight
    }
    float* yb = y + (size_t)b * C_ * HW_ + hw0 + hwL;
#pragma unroll
    for (int ci = 0; ci < 16; ++ci)
      yb[(size_t)(ci * 16 + cq) * HW_] = yv[ci] * iv;
  }
}

// ---------------- host ----------------
extern "C" void kernel_launch(void* const* d_in, const int* in_sizes, int n_in,
                              void* d_out, int out_size, void* d_ws, size_t ws_size,
                              hipStream_t stream) {
  const float* x   = (const float*)d_in[0];      // [32,256,32,32]
  const float* mem = (const float*)d_in[1];      // [2000,256]
  float* y       = (float*)d_out;                              // 8388608 floats
  float* att_out = (float*)d_out + (size_t)B_ * C_ * HW_;      // 65536000 floats

  char* ws = (char*)d_ws;
  _Float16* mh = (_Float16*)ws;                                // 1 MB
  _Float16* ml = (_Float16*)(ws + (size_t)1024 * 1024);        // 1 MB

  prep_memS_kernel<<<dim3(MP_), dim3(K_), 0, stream>>>(mem, mh, ml);
  fused_kernel<<<dim3(N_ / 32), dim3(512), 0, stream>>>(
      x, mh, ml, mem, y, att_out);
}

// Round 6
// 533.653 us; speedup vs baseline: 1.4509x; 1.1517x over previous
//
#include <hip/hip_runtime.h>

// Problem constants
#define B_   32
#define C_   256
#define HW_  1024
#define N_   32768      // B_*HW_
#define M_   2000
#define MP_  2048       // M padded (rows >= 2000 are zero)
#define K_   256

typedef __attribute__((ext_vector_type(8))) _Float16 f16x8;
typedef __attribute__((ext_vector_type(4))) float f32x4;

#define KCAP 32
#define AP   264        // Ahs/Als row stride in halfwords (132 words = 4 mod 32)

#define MFMA16(a, b, c) __builtin_amdgcn_mfma_f32_16x16x32_f16(a, b, c, 0, 0, 0)

// ---------------- prep: mem*64 -> fp16 hi/lo, staged-GEMM layout -----------
// mhs layout: [kslice 8][m 2048][slot 8][hw 8] fp16 (128B per (kslice,m) row).
// slots 0-3 = hi halfwords kk=0..31, slots 4-7 = lo. Stored slot s' = s^(m&7)
// (XOR pre-swizzle; global_load_lds copies linearly -> LDS image is swizzled,
// ds_read applies the same XOR => conflict-free; rule #21 both-sides).
// K itself is nibble-permuted (position p holds channel 16*(p&15)+(p>>4)),
// matching the fused kernel's x-transpose order.
__global__ void prep_memS_kernel(const float* __restrict__ mem,
                                 _Float16* __restrict__ mhs) {
  int m = blockIdx.x;           // 0..2047
  int p = threadIdx.x;          // 0..255 (permuted-k position)
  int c = ((p & 15) << 4) | (p >> 4);
  float v = (m < M_) ? mem[m * K_ + c] * 64.0f : 0.0f;
  _Float16 h = (_Float16)v;
  _Float16 l = (_Float16)(v - (float)h);
  int ks = p >> 5, kk = p & 31;
  int sh = (kk >> 3) ^ (m & 7);
  int sl = ((kk >> 3) + 4) ^ (m & 7);
  size_t base = ((size_t)ks * MP_ + m) * 64;    // 64 halfwords per row
  mhs[base + sh * 8 + (kk & 7)] = h;
  mhs[base + sl * 8 + (kk & 7)] = l;
}

// ---------------- fused: GEMM1 + softmax-threshold + att + sparse GEMM2 ----
// One WG = 32 pixel rows x ALL 2048 m. B staged via double-buffered
// global_load_lds in 64 units (8 kslices x 8 m-chunks of 256), one barrier
// per unit; MFMAs consume buf[t&1] while buf[(t+1)&1] stages (T3-lite).
// Wave w owns, per chunk ch, m = ch*256 + w*32 + mf*16 + row16.
__global__ __launch_bounds__(512, 1) void fused_kernel(
    const float* __restrict__ x, const _Float16* __restrict__ mhs,
    const float* __restrict__ mem,
    float* __restrict__ y, float* __restrict__ att) {
  __shared__ _Float16 Bs[2][256 * 64];    // 2 x 32 KB staged B blocks
  __shared__ _Float16 Ahs[32][AP];        // q hi (n-major, permuted-K rows)
  __shared__ _Float16 Als[32][AP];        // q lo
  __shared__ float S_part[8][32];
  __shared__ float Sthr[32];
  __shared__ float inv_s[32];
  __shared__ unsigned int kcnt[32];
  __shared__ unsigned int km[32][KCAP];
  __shared__ float kp[32][KCAP];

  const int tid   = threadIdx.x;
  const int lane  = tid & 63;
  const int wave  = tid >> 6;        // 0..7
  const int row16 = lane & 15;
  const int quad  = lane >> 4;
  const int r7    = row16 & 7;
  const int n0  = blockIdx.x * 32;
  const int b   = n0 >> 10;
  const int hw0 = n0 & 1023;

  float (*xs)[33] = (float (*)[33])&Bs[0][0];   // 33.8 KB alias (dead before staging)

  // ---- phase 0: stage x[b][*][hw0..hw0+31] -> xs (coalesced) ----
  {
    const int c = tid >> 1;
    const int h16 = (tid & 1) * 16;
    const float* src = x + ((size_t)b * C_ + c) * HW_ + hw0 + h16;
#pragma unroll
    for (int i = 0; i < 4; ++i)
      *(f32x4*)(&xs[c][h16 + i * 4]) = *(const f32x4*)(src + i * 4);
  }
  if (tid < 32) kcnt[tid] = 0;
  __syncthreads();

  // ---- phase 1: transpose-convert xs -> Ahs/Als (fp16 hi/lo, permuted K) --
  {
    const int nl = tid >> 4;             // 0..31
    const int g  = tid & 15;
    f16x8 hi0, hi1, lo0, lo1;
#pragma unroll
    for (int u = 0; u < 8; ++u) {
      float v = xs[u * 16 + g][nl];
      _Float16 h = (_Float16)v;
      hi0[u] = h; lo0[u] = (_Float16)(v - (float)h);
    }
#pragma unroll
    for (int u = 0; u < 8; ++u) {
      float v = xs[(u + 8) * 16 + g][nl];
      _Float16 h = (_Float16)v;
      hi1[u] = h; lo1[u] = (_Float16)(v - (float)h);
    }
    *(f16x8*)(&Ahs[nl][g * 16])     = hi0;
    *(f16x8*)(&Ahs[nl][g * 16 + 8]) = hi1;
    *(f16x8*)(&Als[nl][g * 16])     = lo0;
    *(f16x8*)(&Als[nl][g * 16 + 8]) = lo1;
  }
  __syncthreads();

  // ---- staging helper: one 32KB B block (contiguous in global) ----
#define STAGE(bufidx, unit) do {                                              \
    const _Float16* gs_ = mhs + (size_t)(unit) * 16384;                       \
    _Float16* ld_ = &Bs[bufidx][0];                                           \
    _Pragma("unroll")                                                         \
    for (int i_ = 0; i_ < 4; ++i_) {                                          \
      __builtin_amdgcn_global_load_lds(                                       \
        (const __attribute__((address_space(1))) unsigned int*)(gs_ + (i_ * 512 + tid) * 8), \
        (__attribute__((address_space(3))) unsigned int*)(ld_ + (i_ * 512 + tid) * 8),       \
        16, 0, 0);                                                            \
    }                                                                         \
  } while (0)

  // ---- phase 2: prologue stage of unit 0 (overwrites xs -- dead) ----
  STAGE(0, 0);
  __syncthreads();

  // ---- phase 3: GEMM, 64 units, dbuf pipeline ----
  f32x4 acc[8][2][2];
#pragma unroll
  for (int ch = 0; ch < 8; ++ch)
#pragma unroll
    for (int nf = 0; nf < 2; ++nf)
#pragma unroll
      for (int mf = 0; mf < 2; ++mf) acc[ch][nf][mf] = (f32x4){0.f, 0.f, 0.f, 0.f};

  const int mA = wave * 32;            // wave's m base within each chunk
  const int sH = (quad ^ r7) * 8;      // swizzled hi slot (halfword offset)
  const int sL = ((4 | quad) ^ r7) * 8;

#pragma unroll 1
  for (int ks = 0; ks < 8; ++ks) {
    f16x8 ah[2], al[2];
#pragma unroll
    for (int nf = 0; nf < 2; ++nf) {
      ah[nf] = *(const f16x8*)(&Ahs[nf * 16 + row16][ks * 32 + quad * 8]);
      al[nf] = *(const f16x8*)(&Als[nf * 16 + row16][ks * 32 + quad * 8]);
    }
#pragma unroll
    for (int ch = 0; ch < 8; ++ch) {
      if (ch < 7) { STAGE((ch + 1) & 1, ks * 8 + ch + 1); }
      else if (ks < 7) { STAGE((ch + 1) & 1, ks * 8 + ch + 1); }
      const _Float16* bp0 = &Bs[ch & 1][(mA + row16) * 64];
      f16x8 bh0 = *(const f16x8*)(bp0 + sH);
      f16x8 bl0 = *(const f16x8*)(bp0 + sL);
      f16x8 bh1 = *(const f16x8*)(bp0 + 16 * 64 + sH);
      f16x8 bl1 = *(const f16x8*)(bp0 + 16 * 64 + sL);
      acc[ch][0][0] = MFMA16(ah[0], bh0, acc[ch][0][0]);
      acc[ch][1][0] = MFMA16(ah[1], bh0, acc[ch][1][0]);
      acc[ch][0][1] = MFMA16(ah[0], bh1, acc[ch][0][1]);
      acc[ch][1][1] = MFMA16(ah[1], bh1, acc[ch][1][1]);
      acc[ch][0][0] = MFMA16(al[0], bh0, acc[ch][0][0]);
      acc[ch][1][0] = MFMA16(al[1], bh0, acc[ch][1][0]);
      acc[ch][0][1] = MFMA16(al[0], bh1, acc[ch][0][1]);
      acc[ch][1][1] = MFMA16(al[1], bh1, acc[ch][1][1]);
      acc[ch][0][0] = MFMA16(ah[0], bl0, acc[ch][0][0]);
      acc[ch][1][0] = MFMA16(ah[1], bl0, acc[ch][1][0]);
      acc[ch][0][1] = MFMA16(ah[0], bl1, acc[ch][0][1]);
      acc[ch][1][1] = MFMA16(ah[1], bl1, acc[ch][1][1]);
      __syncthreads();
    }
  }

  // ---- phase 4: exp in place (mask padded m), then S rowsums ----
#pragma unroll
  for (int ch = 0; ch < 8; ++ch)
#pragma unroll
    for (int mf = 0; mf < 2; ++mf) {
      const bool valid = (ch * 256 + mA + mf * 16) < M_;   // wave-uniform
#pragma unroll
      for (int nf = 0; nf < 2; ++nf)
#pragma unroll
        for (int r = 0; r < 4; ++r)
          acc[ch][nf][mf][r] = valid ? __expf(acc[ch][nf][mf][r] * 0.015625f) : 0.f;
    }

  const int nlb = quad * 4;   // row r of frag nf -> n_local = nf*16 + nlb + r
#pragma unroll
  for (int nf = 0; nf < 2; ++nf)
#pragma unroll
    for (int r = 0; r < 4; ++r) {
      float s = 0.f;
#pragma unroll
      for (int ch = 0; ch < 8; ++ch)
        s += acc[ch][nf][0][r] + acc[ch][nf][1][r];
      s += __shfl_xor(s, 1, 16);
      s += __shfl_xor(s, 2, 16);
      s += __shfl_xor(s, 4, 16);
      s += __shfl_xor(s, 8, 16);
      if (row16 == 0) S_part[wave][nf * 16 + nlb + r] = s;
    }
  __syncthreads();
  if (tid < 32) {
    float s = 0.f;
#pragma unroll
    for (int w = 0; w < 8; ++w) s += S_part[w][tid];
    Sthr[tid] = 0.0025f * s;
  }
  __syncthreads();

  // ---- phase 5: keep-scan (S2 + per-row lists) ----
#pragma unroll
  for (int nf = 0; nf < 2; ++nf)
#pragma unroll
    for (int r = 0; r < 4; ++r) {
      const int nl = nf * 16 + nlb + r;
      const float thr = Sthr[nl];
      float s2 = 0.f;
#pragma unroll
      for (int ch = 0; ch < 8; ++ch)
#pragma unroll
        for (int mf = 0; mf < 2; ++mf) {
          const float e = acc[ch][nf][mf][r];
          if (e > thr) {
            s2 += e;
            unsigned int pos = atomicAdd(&kcnt[nl], 1u);
            if (pos < (unsigned)KCAP) {
              km[nl][pos] = (unsigned)(ch * 256 + mA + mf * 16 + row16);
              kp[nl][pos] = e;
            }
          }
        }
      s2 += __shfl_xor(s2, 1, 16);
      s2 += __shfl_xor(s2, 2, 16);
      s2 += __shfl_xor(s2, 4, 16);
      s2 += __shfl_xor(s2, 8, 16);
      if (row16 == 0) S_part[wave][nl] = s2;
    }
  __syncthreads();
  if (tid < 32) {
    float s2 = 0.f;
#pragma unroll
    for (int w = 0; w < 8; ++w) s2 += S_part[w][tid];
    inv_s[tid] = (s2 > 0.f) ? 1.0f / s2 : 0.f;
  }
  __syncthreads();

  // ---- phase 6: att store direct from acc, threshold+scale fused inline ----
  {
    f32x4 thr4[2], iv4[2];
#pragma unroll
    for (int nf = 0; nf < 2; ++nf)
#pragma unroll
      for (int r = 0; r < 4; ++r) {
        thr4[nf][r] = Sthr[nf * 16 + nlb + r];
        iv4[nf][r]  = inv_s[nf * 16 + nlb + r];
      }
    float* attb = att + (size_t)b * M_ * HW_ + hw0;
#pragma unroll
    for (int ch = 0; ch < 8; ++ch)
#pragma unroll
      for (int mf = 0; mf < 2; ++mf) {
        if (ch * 256 + mA + mf * 16 < M_) {   // wave-uniform
          const int m = ch * 256 + mA + mf * 16 + row16;
          float* ar = attb + (size_t)m * HW_ + nlb;
          f32x4 p0, p1;
#pragma unroll
          for (int r = 0; r < 4; ++r) {
            const float e0 = acc[ch][0][mf][r];
            const float e1 = acc[ch][1][mf][r];
            p0[r] = (e0 > thr4[0][r]) ? e0 * iv4[0][r] : 0.f;
            p1[r] = (e1 > thr4[1][r]) ? e1 * iv4[1][r] : 0.f;
          }
          *(f32x4*)(ar)      = p0;
          *(f32x4*)(ar + 16) = p1;
        }
      }
  }

  // ---- phase 7: y sparse GEMM2, k-outer / ci-inner (16-deep MLP) ----
  {
    const int hwL = tid & 31;
    const int cq  = tid >> 5;              // 0..15
    unsigned int kc = kcnt[hwL];
    if (kc > (unsigned)KCAP) kc = KCAP;
    const float iv = inv_s[hwL];
    float yv[16];
#pragma unroll
    for (int ci = 0; ci < 16; ++ci) yv[ci] = 0.f;
#pragma unroll 1
    for (unsigned int k = 0; k < kc; ++k) {
      const float p = kp[hwL][k];
      const float* mrow = mem + (size_t)km[hwL][k] * K_ + cq;
#pragma unroll
      for (int ci = 0; ci < 16; ++ci)
        yv[ci] += p * mrow[ci * 16];
    }
    float* yb = y + (size_t)b * C_ * HW_ + hw0 + hwL;
#pragma unroll
    for (int ci = 0; ci < 16; ++ci)
      yb[(size_t)(ci * 16 + cq) * HW_] = yv[ci] * iv;
  }
#undef STAGE
}

// ---------------- host ----------------
extern "C" void kernel_launch(void* const* d_in, const int* in_sizes, int n_in,
                              void* d_out, int out_size, void* d_ws, size_t ws_size,
                              hipStream_t stream) {
  const float* x   = (const float*)d_in[0];      // [32,256,32,32]
  const float* mem = (const float*)d_in[1];      // [2000,256]
  float* y       = (float*)d_out;                              // 8388608 floats
  float* att_out = (float*)d_out + (size_t)B_ * C_ * HW_;      // 65536000 floats

  _Float16* mhs = (_Float16*)d_ws;               // 2 MB staged-B layout

  prep_memS_kernel<<<dim3(MP_), dim3(K_), 0, stream>>>(mem, mhs);
  fused_kernel<<<dim3(N_ / 32), dim3(512), 0, stream>>>(
      x, mhs, mem, y, att_out);
}